// Round 2
// baseline (882.976 us; speedup 1.0000x reference)
//
#include <hip/hip_runtime.h>
#include <cstdint>
#include <cstddef>

#define T_TASKS 32
#define S_SHOT  2048
#define F_FEAT  1024
#define C_CLS   512
#define MARGIN  0.1f

typedef _Float16 f16;
typedef _Float16 f16x8 __attribute__((ext_vector_type(8)));
typedef float    f32x4 __attribute__((ext_vector_type(4)));

// Wh layout (fragment-major, ready for direct per-wave dwordx4 loads):
//   frag (t,kt,ct) occupies 512 f16 starting at ((t*32+kt)*32+ct)*512.
//   Within a frag, lane ln = q*16+m holds W[t, ct*16+m, kt*32+q*8+j] at ln*8+j.

__device__ __forceinline__ void upd3(float v, int i,
                                     float& v1, int& i1,
                                     float& v2, int& i2,
                                     float& v3, int& i3) {
  if (v > v1 || (v == v1 && i < i1)) { v3=v2; i3=i2; v2=v1; i2=i1; v1=v; i1=i; }
  else if (v > v2 || (v == v2 && i < i2)) { v3=v2; i3=i2; v2=v; i2=i; }
  else if (v > v3 || (v == v3 && i < i3)) { v3=v; i3=i; }
}

__device__ __forceinline__ void cvt8(float4 a, float4 b, f16x8& h, f16x8& l) {
  float f[8] = {a.x, a.y, a.z, a.w, b.x, b.y, b.z, b.w};
#pragma unroll
  for (int j = 0; j < 8; ++j) {
    f16 hj = (f16)f[j];
    h[j] = hj;
    l[j] = (f16)(f[j] - (float)hj);
  }
}

__global__ __launch_bounds__(256) void zero_wsq(float* wsq) {
  wsq[blockIdx.x * 256 + threadIdx.x] = 0.f;
}

// ---------------------------------------------------------------------------
// prep: block = (t, kt). Reads W[t, :, kt*32..+32] (512 rows x 128B),
// writes one 32KB fragment-major chunk (256B-contiguous store segments),
// atomically accumulates 0.5*sum(w^2) partials into wsq.
// ---------------------------------------------------------------------------
__global__ __launch_bounds__(512) void prep_w(const float* __restrict__ W,
                                              f16* __restrict__ Wh,
                                              float* __restrict__ wsq) {
  const int bx = blockIdx.x;
  const int t = bx >> 5, kt = bx & 31;
  const int c = threadIdx.x;               // class 0..511
  const float* wr = W + ((size_t)(t * C_CLS + c)) * F_FEAT + kt * 32;
  float v[32];
  float s = 0.f;
#pragma unroll
  for (int i = 0; i < 8; ++i) {
    float4 x = *(const float4*)(wr + i * 4);
    v[i*4+0] = x.x; v[i*4+1] = x.y; v[i*4+2] = x.z; v[i*4+3] = x.w;
    s += x.x*x.x + x.y*x.y + x.z*x.z + x.w*x.w;
  }
  const int ct = c >> 4, m = c & 15;
  f16* base = Wh + ((size_t)((t * 32 + kt) * 32 + ct)) * 512 + m * 8;
#pragma unroll
  for (int q = 0; q < 4; ++q) {
    f16x8 h;
#pragma unroll
    for (int j = 0; j < 8; ++j) h[j] = (f16)v[q * 8 + j];
    *(f16x8*)(base + q * 128) = h;         // lane stride 16B -> 256B segments
  }
  atomicAdd(&wsq[t * C_CLS + c], 0.5f * s);
}

// ---------------------------------------------------------------------------
// Main: block = (task, 64 rows) x 512 classes; 4 waves = 2 rg x 2 cg.
// Barrier-free K-loop: X per-lane register loads (1-iter prefetch) with
// in-register hi/lo f16 split; W fragments loaded straight from Wh (L2).
// Fused argmax + margin gate + fp64 refinement (unchanged from round 1).
// ---------------------------------------------------------------------------
__global__ __launch_bounds__(256, 2) void gemm_argmax(
    const float* __restrict__ X, const float* __restrict__ W,
    const f16* __restrict__ Wh, const float* __restrict__ wsq,
    int* __restrict__ out) {
  __shared__ float swsq[C_CLS];
  __shared__ float cv[64][2][3];
  __shared__ int   ci[64][2][3];
  __shared__ int   amb_cnt;
  __shared__ int   amb_list[64];

  const int tid = threadIdx.x;
  const int wv  = tid >> 6, ln = tid & 63;
  const int rg  = wv >> 1, cg = wv & 1;
  const int m   = ln & 15, q = ln >> 4;
  const int bx  = blockIdx.x;
  const int t   = bx & 31, rb = bx >> 5;   // task->XCD affinity (bx%8 == t%8)
  const int row0 = rb * 64;

  swsq[tid]       = wsq[t * C_CLS + tid];
  swsq[tid + 256] = wsq[t * C_CLS + tid + 256];
  if (tid == 0) amb_cnt = 0;
  __syncthreads();                          // swsq ready; no barriers after

  const f32x4 zero4 = {0.f, 0.f, 0.f, 0.f};
  f32x4 acc[2][16];
#pragma unroll
  for (int a = 0; a < 2; ++a)
#pragma unroll
    for (int b = 0; b < 16; ++b) acc[a][b] = zero4;

  // per-lane X row pointers (A-fragment elements only)
  const float* x0 = X + ((size_t)(t * S_SHOT + row0 + rg * 32 + m)) * F_FEAT + q * 8;
  const float* x1 = x0 + (size_t)16 * F_FEAT;
  // per-lane W fragment pointer for this wave's class half
  const f16* wt = Wh + ((size_t)t * 32 * 32 * 512) + (size_t)(cg * 16) * 512 + ln * 8;

  float4 p0a = *(const float4*)(x0);
  float4 p0b = *(const float4*)(x0 + 4);
  float4 p1a = *(const float4*)(x1);
  float4 p1b = *(const float4*)(x1 + 4);

#pragma unroll 2
  for (int kt = 0; kt < 32; ++kt) {
    const int kn = (kt < 31) ? (kt + 1) : 31;
    float4 n0a = *(const float4*)(x0 + kn * 32);
    float4 n0b = *(const float4*)(x0 + kn * 32 + 4);
    float4 n1a = *(const float4*)(x1 + kn * 32);
    float4 n1b = *(const float4*)(x1 + kn * 32 + 4);

    f16x8 ah0, al0, ah1, al1;
    cvt8(p0a, p0b, ah0, al0);
    cvt8(p1a, p1b, ah1, al1);

    const f16* bp = wt + (size_t)kt * 16384;
    f16x8 b[16];
#pragma unroll
    for (int i = 0; i < 16; ++i) b[i] = *(const f16x8*)(bp + i * 512);
#pragma unroll
    for (int i = 0; i < 16; ++i) {
      acc[0][i] = __builtin_amdgcn_mfma_f32_16x16x32_f16(ah0, b[i], acc[0][i], 0, 0, 0);
      acc[0][i] = __builtin_amdgcn_mfma_f32_16x16x32_f16(al0, b[i], acc[0][i], 0, 0, 0);
      acc[1][i] = __builtin_amdgcn_mfma_f32_16x16x32_f16(ah1, b[i], acc[1][i], 0, 0, 0);
      acc[1][i] = __builtin_amdgcn_mfma_f32_16x16x32_f16(al1, b[i], acc[1][i], 0, 0, 0);
    }
    p0a = n0a; p0b = n0b; p1a = n1a; p1b = n1b;
  }

  // ---- epilogue: top-3 per (row, col-half); C/D: col=lane&15, row=q*4+reg
  const int c0 = cg * 256 + m;
#pragma unroll
  for (int rt = 0; rt < 2; ++rt) {
#pragma unroll
    for (int rr = 0; rr < 4; ++rr) {
      float v1 = -3.4e38f, v2 = -3.4e38f, v3 = -3.4e38f;
      int   i1 = 0x7fffffff, i2 = 0x7fffffff, i3 = 0x7fffffff;
#pragma unroll
      for (int ct = 0; ct < 16; ++ct) {
        int cidx = c0 + ct * 16;
        float sc = acc[rt][ct][rr] - swsq[cidx];
        upd3(sc, cidx, v1, i1, v2, i2, v3, i3);
      }
      for (int off = 1; off < 16; off <<= 1) {
        float w1 = __shfl_xor(v1, off); int j1 = __shfl_xor(i1, off);
        float w2 = __shfl_xor(v2, off); int j2 = __shfl_xor(i2, off);
        float w3 = __shfl_xor(v3, off); int j3 = __shfl_xor(i3, off);
        upd3(w1, j1, v1, i1, v2, i2, v3, i3);
        upd3(w2, j2, v1, i1, v2, i2, v3, i3);
        upd3(w3, j3, v1, i1, v2, i2, v3, i3);
      }
      if (m == 0) {
        int row = rg * 32 + rt * 16 + q * 4 + rr;
        cv[row][cg][0] = v1; ci[row][cg][0] = i1;
        cv[row][cg][1] = v2; ci[row][cg][1] = i2;
        cv[row][cg][2] = v3; ci[row][cg][2] = i3;
      }
    }
  }
  __syncthreads();

  // ---- gate: write confident rows; queue ambiguous ones
  if (tid < 64) {
    float a1 = cv[tid][0][0]; int aj = ci[tid][0][0];
    float b1 = cv[tid][1][0]; int bj = ci[tid][1][0];
    float win, runner; int widx;
    if (a1 > b1 || (a1 == b1 && aj < bj)) {
      win = a1; widx = aj; runner = fmaxf(b1, cv[tid][0][1]);
    } else {
      win = b1; widx = bj; runner = fmaxf(a1, cv[tid][1][1]);
    }
    if (win - runner >= MARGIN) {
      out[t * S_SHOT + row0 + tid] = widx;
    } else {
      int p = atomicAdd(&amb_cnt, 1);
      amb_list[p] = tid;
    }
  }
  __syncthreads();

  // ---- fp64 refinement of ambiguous rows (expected ~0.5 per block)
  int nA = amb_cnt;
  for (int a = wv; a < nA; a += 4) {
    int rl = amb_list[a];
    const float* xr = X + ((size_t)t * S_SHOT + row0 + rl) * F_FEAT;
    double best = -1.0e300; int bidx = 0x7fffffff;
    for (int g = 0; g < 2; ++g) {
      for (int k = 0; k < 3; ++k) {
        int cidx = ci[rl][g][k];
        const float* wr = W + ((size_t)t * C_CLS + cidx) * F_FEAT;
        double sd = 0.0, sw = 0.0;
        for (int j = 0; j < 16; ++j) {
          float xv  = xr[ln + 64 * j];
          float wv2 = wr[ln + 64 * j];
          sd += (double)xv * (double)wv2;
          sw += (double)wv2 * (double)wv2;
        }
#pragma unroll
        for (int off = 32; off > 0; off >>= 1) {
          sd += __shfl_xor(sd, off);
          sw += __shfl_xor(sw, off);
        }
        double sc = sd - 0.5 * sw;
        if (sc > best || (sc == best && cidx < bidx)) { best = sc; bidx = cidx; }
      }
    }
    if (ln == 0) out[t * S_SHOT + row0 + rl] = bidx;
  }
}

extern "C" void kernel_launch(void* const* d_in, const int* in_sizes, int n_in,
                              void* d_out, int out_size, void* d_ws, size_t ws_size,
                              hipStream_t stream) {
  (void)in_sizes; (void)n_in; (void)out_size;
  const float* X = (const float*)d_in[0];
  const float* W = (const float*)d_in[1];
  // temp (d_in[2]) is argmax-invariant; unused.
  const size_t wh_bytes = (size_t)T_TASKS * C_CLS * F_FEAT * sizeof(f16); // 33.5MB
  const size_t need = wh_bytes + (size_t)T_TASKS * C_CLS * sizeof(float);
  if (ws_size < need) return;
  f16*   Wh  = (f16*)d_ws;
  float* wsq = (float*)((char*)d_ws + wh_bytes);
  int*   out = (int*)d_out;
  zero_wsq<<<T_TASKS * C_CLS / 256, 256, 0, stream>>>(wsq);
  prep_w<<<T_TASKS * 32, 512, 0, stream>>>(W, Wh, wsq);
  gemm_argmax<<<T_TASKS * (S_SHOT / 64), 256, 0, stream>>>(X, W, Wh, wsq, out);
}